// Round 5
// baseline (1140.488 us; speedup 1.0000x reference)
//
#include <hip/hip_runtime.h>
#include <hip/hip_fp16.h>

// WindowAttention fused kernel for MI355X (gfx950).
// B=4096 windows, N=49 tokens (pad 64), C=192, H=6, hd=32.
// V5 (resubmit; round-4 bench was an infra failure - container died twice,
// kernel never ran): 512-thread blocks (8 waves), 3 blocks/CU (LDS 53,248 B),
// head-units (strip,head) split across waves -> per-block chain ~halves and
// 6 waves/SIMD hide latency. Q computed as Q^T = Wq x^T and kept IN REGISTERS
// (B-frag via the verified cross-lq pack+shuffle) -> Qall LDS eliminated.
// K/V col-owned (weights once); proj partials pair-reduced via LDS at the
// end. No barriers in the head loop.

typedef short bf16x8 __attribute__((ext_vector_type(8)));
typedef float f32x4 __attribute__((ext_vector_type(4)));

#define MFMA16(a, b, c) __builtin_amdgcn_mfma_f32_16x16x32_bf16((a), (b), (c), 0, 0, 0)

#define DIMC 192
#define NTOK 49

// round-to-nearest-even fp32 -> bf16
__device__ __forceinline__ unsigned short f2bf(float f) {
  unsigned int u = __float_as_uint(f);
  u += 0x7fffu + ((u >> 16) & 1u);
  return (unsigned short)(u >> 16);
}

// packed fp32x2 -> bf16x2 (RNE), single VALU op
__device__ __forceinline__ unsigned int cvt_pk_bf16(float lo, float hi) {
  unsigned int r;
  asm("v_cvt_pk_bf16_f32 %0, %1, %2" : "=v"(r) : "v"(lo), "v"(hi));
  return r;
}

// prep: bf16 weights + combined (bias+mask)*log2e fp16 table, frag-permuted:
// bm[widx][h] tile of 4096 halfs, offset = ((nt*4 + lq)*64 + q)*4 + r,
// value = (bias[h][q][k] + mask[widx][q][k]) * log2e, k = nt*16 + lq*4 + r.
// k >= 49 -> -30000*log2e, q >= 49 -> 0 (rows discarded).
__global__ void prep_kernel(const float* __restrict__ qkv_w,
                            const float* __restrict__ proj_w,
                            const float* __restrict__ bias_table,
                            const int* __restrict__ rel_idx,
                            const float* __restrict__ mask,
                            unsigned short* __restrict__ qkv_wb,
                            unsigned short* __restrict__ proj_wb,
                            __half* __restrict__ bmT) {
  const float LOG2E = 1.4426950408889634f;
  int i = blockIdx.x * 256 + threadIdx.x;
  if (i < 576 * 192) qkv_wb[i] = f2bf(qkv_w[i]);
  if (i < 192 * 192) proj_wb[i] = f2bf(proj_w[i]);
  {
    int r = i & 3;
    int q = (i >> 2) & 63;
    int lq = (i >> 8) & 3;
    int nt = (i >> 10) & 3;
    int hw = i >> 12;          // widx*6 + h
    int h = hw % 6;
    int widx = hw / 6;
    int k = nt * 16 + lq * 4 + r;
    float v;
    if (k >= NTOK) v = -30000.f * LOG2E;
    else if (q >= NTOK) v = 0.f;
    else v = (bias_table[rel_idx[q * NTOK + k] * 6 + h] +
              mask[(size_t)widx * (NTOK * NTOK) + q * NTOK + k]) * LOG2E;
    bmT[i] = __float2half(v);
  }
}

__global__ __launch_bounds__(512, 6) void winattn_kernel(
    const float* __restrict__ x,
    const float* __restrict__ qkv_b,
    const float* __restrict__ proj_b,
    const unsigned short* __restrict__ qkv_wb,
    const unsigned short* __restrict__ proj_wb,
    const __half* __restrict__ bmT,
    float* __restrict__ out) {
  // LDS pool: 53,248 B -> 3 blocks/CU. xb aliases Kall (dead after reg hoist);
  // scr (final f32 reduce) aliases the whole pool (dead after head loop).
  __shared__ unsigned short pool[26624];
  unsigned short* xb   = pool;            // [64][200] bf16 x (transient)
  unsigned short* Kall = pool;            // [64 tok][200], cols 0..191
  unsigned short* Vta  = pool + 12800;    // [192 d][72 tok]  (V^T, all heads)
  float* scr = (float*)pool;              // [4 strip][16][196] f32 (final)

  const int tid = threadIdx.x;
  const int b = blockIdx.x;
  const int widx = b & 63;
  const int lane = tid & 63;
  const int wv = tid >> 6;          // wave 0..7
  const int lq = lane >> 4;         // quad 0..3
  const int ln = lane & 15;
  const int strip = wv >> 1;        // q-row strip 0..3 (rows strip*16..+15)
  const int hsel = wv & 1;          // head group: hsel*3 .. hsel*3+2

  // ---------------- stage x (bf16, zero rows >= 49)
  {
    const float4* xp = (const float4*)(x + (size_t)b * (NTOK * DIMC));
    for (int i = tid; i < NTOK * DIMC / 4; i += 512) {
      float4 v = xp[i];
      int fl = i * 4;
      int r = fl / DIMC;
      int c = fl - r * DIMC;
      unsigned int lo = (unsigned int)f2bf(v.x) | ((unsigned int)f2bf(v.y) << 16);
      unsigned int hi = (unsigned int)f2bf(v.z) | ((unsigned int)f2bf(v.w) << 16);
      *(uint2*)(&xb[r * 200 + c]) = make_uint2(lo, hi);
    }
    for (int i = tid; i < 15 * 200 / 2; i += 512)
      ((unsigned int*)(&xb[49 * 200]))[i] = 0u;
  }
  __syncthreads();

  // ---------------- hoist x into registers as MFMA A/B-frags.
  // af[mt][ks]: rows mt*16+ln, k = ks*32 + lq*8..+7. afs = wave's own strip
  // (separate copy so all indexing stays compile-time constant).
  bf16x8 af[4][6];
#pragma unroll
  for (int mt = 0; mt < 4; ++mt)
#pragma unroll
    for (int ks = 0; ks < 6; ++ks)
      af[mt][ks] = *(const bf16x8*)&xb[(mt * 16 + ln) * 200 + ks * 32 + lq * 8];
  bf16x8 afs[6];
#pragma unroll
  for (int ks = 0; ks < 6; ++ks)
    afs[ks] = *(const bf16x8*)&xb[(strip * 16 + ln) * 200 + ks * 32 + lq * 8];
  __syncthreads();  // xb dead; its LDS becomes Kall

  // scale * log2e: softmax runs in exp2 domain
  const float scale2 = 0.17677669529663687f * 1.4426950408889634f;
  const int sA = ((lq & 1) << 5) | ln;   // cross-lq exchange source lanes
  const int sB = sA + 16;
  const int hiSel = lq >> 1;
  union U8 { unsigned int u[4]; bf16x8 v; };

  // ---------------- Q^T = Wq x^T for this wave's 3 heads (d = hsel*96..+95),
  // tok strip = strip. C-frag: row d-off = lq*4+r, col tok = strip*16+ln.
  unsigned int pkQ[6][2];
  const int dbase = hsel * 96;
#pragma unroll
  for (int ct = 0; ct < 6; ++ct) {
    const unsigned short* wp = qkv_wb + (size_t)(dbase + ct * 16 + ln) * DIMC + lq * 8;
    bf16x8 wf[6];
#pragma unroll
    for (int ks = 0; ks < 6; ++ks) wf[ks] = *(const bf16x8*)(wp + ks * 32);
    float4 bq = *(const float4*)&qkv_b[dbase + ct * 16 + lq * 4];
    f32x4 acc = (f32x4){bq.x, bq.y, bq.z, bq.w};
#pragma unroll
    for (int ks = 0; ks < 6; ++ks) acc = MFMA16(wf[ks], afs[ks], acc);
    pkQ[ct][0] = cvt_pk_bf16(acc[0] * scale2, acc[1] * scale2);
    pkQ[ct][1] = cvt_pk_bf16(acc[2] * scale2, acc[3] * scale2);
  }
  // C-frag -> attention B-frag (same exchange as oa): qb[hh] elem j at (lq,ln)
  // = Q[tok=strip*16+ln][dbase + hh*32 + lq*8 + j]
  U8 qb[3];
#pragma unroll
  for (int hh = 0; hh < 3; ++hh)
#pragma unroll
    for (int w = 0; w < 4; ++w) {
      int src = (w & 2) ? sB : sA;
      int a0 = __shfl((int)pkQ[2 * hh][w & 1], src, 64);
      int a1 = __shfl((int)pkQ[2 * hh + 1][w & 1], src, 64);
      qb[hh].u[w] = (unsigned int)(hiSel ? a1 : a0);
    }

  // ---------------- K/V: 24 col-tiles / 8 waves = 3 each, full-m (weights 1x)
  for (int i = 0; i < 3; ++i) {
    int t = wv * 3 + i;                      // 0..23
    int isK = (t < 12);
    int colt = isK ? t : (t - 12);
    int row = (isK ? 192 : 384) + colt * 16 + ln;   // qkv_wb row
    const unsigned short* wp = qkv_wb + (size_t)row * DIMC + lq * 8;
    bf16x8 wf[6];
#pragma unroll
    for (int ks = 0; ks < 6; ++ks) wf[ks] = *(const bf16x8*)(wp + ks * 32);
    float bv = qkv_b[row];
    f32x4 a0 = (f32x4){bv, bv, bv, bv};
    f32x4 a1 = a0, a2 = a0, a3 = a0;
#pragma unroll
    for (int ks = 0; ks < 6; ++ks) {
      a0 = MFMA16(af[0][ks], wf[ks], a0);
      a1 = MFMA16(af[1][ks], wf[ks], a1);
      a2 = MFMA16(af[2][ks], wf[ks], a2);
      a3 = MFMA16(af[3][ks], wf[ks], a3);
    }
    f32x4 acc[4] = {a0, a1, a2, a3};
    int db = colt * 16 + ln;
    if (isK) {
#pragma unroll
      for (int mt = 0; mt < 4; ++mt) {
        int row0 = mt * 16 + lq * 4;
#pragma unroll
        for (int r = 0; r < 4; ++r)
          Kall[(row0 + r) * 200 + db] = f2bf(acc[mt][r]);
      }
    } else {
#pragma unroll
      for (int mt = 0; mt < 4; ++mt) {
        int row0 = mt * 16 + lq * 4;
        unsigned int lo = cvt_pk_bf16(acc[mt][0], acc[mt][1]);
        unsigned int hi = cvt_pk_bf16(acc[mt][2], acc[mt][3]);
        *(uint2*)(&Vta[db * 72 + row0]) = make_uint2(lo, hi);
      }
    }
  }
  __syncthreads();  // K/V^T (all heads) ready; NO barriers in head loop.

  // persistent proj accumulators: wave's strip rows, all 192 cols; bias only
  // on even waves (partials get summed pairwise at the end).
  f32x4 pacc[12];
#pragma unroll
  for (int nti = 0; nti < 12; ++nti) {
    float pbv = hsel ? 0.f : proj_b[nti * 16 + ln];
    pacc[nti] = (f32x4){pbv, pbv, pbv, pbv};
  }

  const __half* bmp = bmT + (size_t)widx * 6 * 4096;

  // ---------------- head loop: 3 units (strip, h = hsel*3+hh)
  for (int hh = 0; hh < 3; ++hh) {
    const int h = hsel * 3 + hh;
    // bias+mask fragments: k = nt*16+lq*4+{0..3}, q = strip*16+ln
    uint2 bmu[4];
    {
      const __half* bmh = bmp + (size_t)h * 4096;
#pragma unroll
      for (int nt = 0; nt < 4; ++nt)
        bmu[nt] = *(const uint2*)(bmh + ((nt * 4 + lq) * 64 + strip * 16 + ln) * 4);
    }

    // S^T = K Q^T : A = K rows (token = nt*16+ln), B = qb (regs)
    f32x4 sv[4];
#pragma unroll
    for (int nt = 0; nt < 4; ++nt) {
      bf16x8 kf = *(const bf16x8*)&Kall[(nt * 16 + ln) * 200 + h * 32 + lq * 8];
      sv[nt] = MFMA16(kf, qb[hh].v, ((f32x4){0.f, 0.f, 0.f, 0.f}));
    }
    float tt[4][4];
#pragma unroll
    for (int nt = 0; nt < 4; ++nt) {
      float2 f01 = __half22float2(*(const __half2*)&bmu[nt].x);
      float2 f23 = __half22float2(*(const __half2*)&bmu[nt].y);
      tt[nt][0] = sv[nt][0] + f01.x;
      tt[nt][1] = sv[nt][1] + f01.y;
      tt[nt][2] = sv[nt][2] + f23.x;
      tt[nt][3] = sv[nt][3] + f23.y;
    }
    // softmax over k (exp2 domain): tree max/sum in-lane + 2-step lq reduce
    float m0 = fmaxf(fmaxf(tt[0][0], tt[0][1]), fmaxf(tt[0][2], tt[0][3]));
    float m1 = fmaxf(fmaxf(tt[1][0], tt[1][1]), fmaxf(tt[1][2], tt[1][3]));
    float m2 = fmaxf(fmaxf(tt[2][0], tt[2][1]), fmaxf(tt[2][2], tt[2][3]));
    float m3 = fmaxf(fmaxf(tt[3][0], tt[3][1]), fmaxf(tt[3][2], tt[3][3]));
    float m = fmaxf(fmaxf(m0, m1), fmaxf(m2, m3));
    m = fmaxf(m, __shfl_xor(m, 16, 64));
    m = fmaxf(m, __shfl_xor(m, 32, 64));
    float s[4];
#pragma unroll
    for (int nt = 0; nt < 4; ++nt) {
      float e0 = exp2f(tt[nt][0] - m);
      float e1 = exp2f(tt[nt][1] - m);
      float e2 = exp2f(tt[nt][2] - m);
      float e3 = exp2f(tt[nt][3] - m);
      tt[nt][0] = e0; tt[nt][1] = e1; tt[nt][2] = e2; tt[nt][3] = e3;
      s[nt] = (e0 + e1) + (e2 + e3);
    }
    float sum = (s[0] + s[1]) + (s[2] + s[3]);
    sum += __shfl_xor(sum, 16, 64);
    sum += __shfl_xor(sum, 32, 64);
    float pinv = 1.f / sum;

    // pack P^T, redistribute to PV B-frags
    unsigned int pk[4][2];
#pragma unroll
    for (int nt = 0; nt < 4; ++nt) {
      pk[nt][0] = cvt_pk_bf16(tt[nt][0], tt[nt][1]);
      pk[nt][1] = cvt_pk_bf16(tt[nt][2], tt[nt][3]);
    }
    U8 pb0, pb1;
#pragma unroll
    for (int w = 0; w < 4; ++w) {
      int src = (w & 2) ? sB : sA;
      int a0 = __shfl((int)pk[0][w & 1], src, 64);
      int a1 = __shfl((int)pk[1][w & 1], src, 64);
      int b0 = __shfl((int)pk[2][w & 1], src, 64);
      int b1 = __shfl((int)pk[3][w & 1], src, 64);
      pb0.u[w] = (unsigned int)(hiSel ? a1 : a0);
      pb1.u[w] = (unsigned int)(hiSel ? b1 : b0);
    }
    // O^T = V^T P^T : A = V^T rows (d = h*32 + db*16+ln)
    f32x4 o[2];
#pragma unroll
    for (int db = 0; db < 2; ++db) {
      bf16x8 v0 = *(const bf16x8*)&Vta[(h * 32 + db * 16 + ln) * 72 + lq * 8];
      bf16x8 v1 = *(const bf16x8*)&Vta[(h * 32 + db * 16 + ln) * 72 + 32 + lq * 8];
      f32x4 acc = (f32x4){0.f, 0.f, 0.f, 0.f};
      acc = MFMA16(v0, pb0.v, acc);
      acc = MFMA16(v1, pb1.v, acc);
      o[db] = acc;
    }
    // normalize + pack O^T, redistribute to proj A-frag
    unsigned int pkO[2][2];
#pragma unroll
    for (int db = 0; db < 2; ++db) {
      pkO[db][0] = cvt_pk_bf16(o[db][0] * pinv, o[db][1] * pinv);
      pkO[db][1] = cvt_pk_bf16(o[db][2] * pinv, o[db][3] * pinv);
    }
    U8 oa;
#pragma unroll
    for (int w = 0; w < 4; ++w) {
      int src = (w & 2) ? sB : sA;
      int a0 = __shfl((int)pkO[0][w & 1], src, 64);
      int a1 = __shfl((int)pkO[1][w & 1], src, 64);
      oa.u[w] = (unsigned int)(hiSel ? a1 : a0);
    }
    // partial proj: A = O rows (q = strip*16+ln, d = lq*8..+7), K=32 slice
#pragma unroll
    for (int nti = 0; nti < 12; ++nti) {
      bf16x8 w = *(const bf16x8*)(proj_wb +
          (size_t)(nti * 16 + ln) * DIMC + h * 32 + lq * 8);
      pacc[nti] = MFMA16(oa.v, w, pacc[nti]);
    }
  }

  // ---------------- pairwise proj reduce via LDS (K/V pool dead), then store
  __syncthreads();
  if (hsel) {
    float* sp = scr + strip * (16 * 196);
#pragma unroll
    for (int nti = 0; nti < 12; ++nti)
#pragma unroll
      for (int r = 0; r < 4; ++r)
        sp[(lq * 4 + r) * 196 + nti * 16 + ln] = pacc[nti][r];
  }
  __syncthreads();
  if (!hsel) {
    float* outp = out + (size_t)b * (NTOK * DIMC);
    const float* sp = scr + strip * (16 * 196);
#pragma unroll
    for (int nti = 0; nti < 12; ++nti) {
      int col = nti * 16 + ln;
#pragma unroll
      for (int r = 0; r < 4; ++r) {
        int row = strip * 16 + lq * 4 + r;
        if (row < NTOK)
          outp[row * DIMC + col] = pacc[nti][r] + sp[(lq * 4 + r) * 196 + col];
      }
    }
  }
}

extern "C" void kernel_launch(void* const* d_in, const int* in_sizes, int n_in,
                              void* d_out, int out_size, void* d_ws, size_t ws_size,
                              hipStream_t stream) {
  const float* x = (const float*)d_in[0];
  const float* mask = (const float*)d_in[1];
  const float* qkv_w = (const float*)d_in[2];
  const float* qkv_b = (const float*)d_in[3];
  const float* proj_w = (const float*)d_in[4];
  const float* proj_b = (const float*)d_in[5];
  const float* bias_table = (const float*)d_in[6];
  const int* rel_idx = (const int*)d_in[7];

  unsigned short* qkv_wb = (unsigned short*)d_ws;                 // 576*192 bf16
  unsigned short* proj_wb = qkv_wb + 576 * 192;                   // 192*192 bf16
  __half* bmT = (__half*)(proj_wb + 192 * 192);                   // 64*6*4096 fp16

  prep_kernel<<<6144, 256, 0, stream>>>(qkv_w, proj_w, bias_table, rel_idx,
                                        mask, qkv_wb, proj_wb, bmT);
  winattn_kernel<<<4096, 512, 0, stream>>>(x, qkv_b, proj_b,
                                           qkv_wb, proj_wb, bmT,
                                           (float*)d_out);
}